// Round 19
// baseline (915.569 us; speedup 1.0000x reference)
//
#include <hip/hip_runtime.h>
#include <math.h>

#define B_    4096
#define N_    3400
#define NP2_  3584          // scores N padded to 256 (over-read, cols discarded)
#define D1_   2048
#define D2_   1024
#define E_    10
#define NE_   (E_ * D2_)    // 10240 fused ensemble columns
#define NDOT_ 256           // extra dot columns (170 used)
#define NEX_  (NE_ + NDOT_) // 10496
#define ZOFF_ 3456          // z rows start in SZ
#define MR_   7680          // SZ total rows (3456 S + 4096 z + 128 pad)
#define EC_   170           // E_*C_
#define C_    17
#define TOPK_ 20
#define CAND_ 24            // bf16-score candidates kept for exact rescore
#define TAU_  10.0f

typedef __bf16 bf16x8 __attribute__((ext_vector_type(8)));
typedef __bf16 bf16x4 __attribute__((ext_vector_type(4)));
typedef float  f32x4  __attribute__((ext_vector_type(4)));

#define MFMA_(a,b,c) __builtin_amdgcn_mfma_f32_16x16x32_bf16(a,b,c,0,0,0)

__device__ inline float wsum64(float v){
  #pragma unroll
  for (int m = 1; m < 64; m <<= 1) v += __shfl_xor(v, m);
  return v;
}

__device__ __forceinline__ void gload_lds16(const unsigned short* g, unsigned short* l){
  __builtin_amdgcn_global_load_lds(
      (const __attribute__((address_space(1))) void*)g,
      (__attribute__((address_space(3))) void*)l, 16, 0, 0);
}

// fused: row 1/max(||x||,eps) + fp32 -> hi bf16, one pass
__global__ __launch_bounds__(256)
void prep_rows(const float* __restrict__ X, unsigned short* __restrict__ hi,
               float* __restrict__ rinv){
  const int r = blockIdx.x, t = threadIdx.x;
  const float4* x4 = reinterpret_cast<const float4*>(X + (long)r * D1_);
  bf16x4* h4 = reinterpret_cast<bf16x4*>(hi + (long)r * D1_);
  float ss = 0.f;
  #pragma unroll
  for (int it = 0; it < 2; ++it){
    int i = t + it * 256;
    float4 v = x4[i];
    float f[4] = {v.x, v.y, v.z, v.w};
    bf16x4 h;
    #pragma unroll
    for (int j = 0; j < 4; ++j){
      ss += f[j] * f[j];
      h[j] = (__bf16)f[j];
    }
    h4[i] = h;
  }
  __shared__ float red[256];
  red[t] = ss; __syncthreads();
  for (int s = 128; s; s >>= 1){ if (t < s) red[t] += red[t + s]; __syncthreads(); }
  if (t == 0) rinv[r] = 1.f / fmaxf(sqrtf(red[0]), 1e-12f);
}

// one kernel zeroing all pad/accumulator regions
__global__ __launch_bounds__(256)
void zfill_all(uint4* p0, long n0, uint4* p1, long n1, uint4* p2, long n2,
               uint4* p3, long n3, uint4* p4, long n4){
  long i = (long)blockIdx.x * 256 + threadIdx.x;
  uint4 zz = make_uint4(0,0,0,0);
  if (i < n0){ p0[i] = zz; return; } i -= n0;
  if (i < n1){ p1[i] = zz; return; } i -= n1;
  if (i < n2){ p2[i] = zz; return; } i -= n2;
  if (i < n3){ p3[i] = zz; return; } i -= n3;
  if (i < n4){ p4[i] = zz; }
}

__global__ __launch_bounds__(256)
void labelprep(const float* __restrict__ labels, int* __restrict__ y, float* __restrict__ cnt){
  int n = blockIdx.x * 256 + threadIdx.x;
  if (n >= N_) return;
  int c = 0;
  #pragma unroll
  for (int cc = 0; cc < C_; ++cc) if (labels[n * C_ + cc] > 0.5f) c = cc;
  y[n] = c;
  atomicAdd(&cnt[c], 1.0f);
}

// Wbf[e][n][k] = bf16(alpha[e][k] * W[n][k]),  laid out [NE_][D1_]
__global__ __launch_bounds__(256)
void wfold(const float* __restrict__ W, const float* __restrict__ alpha,
           unsigned short* __restrict__ wbf){
  long i = (long)blockIdx.x * 256 + threadIdx.x;       // float4 units
  const long perE = (long)D2_ * D1_ / 4;
  int e = (int)(i / perE);
  long r = i - (long)e * perE;
  int k4 = (int)(r & (D1_/4 - 1));
  float4 wv = reinterpret_cast<const float4*>(W)[r];
  float4 av = reinterpret_cast<const float4*>(alpha + (long)e * D1_)[k4];
  bf16x4 o;
  o[0] = (__bf16)(wv.x * av.x);
  o[1] = (__bf16)(wv.y * av.y);
  o[2] = (__bf16)(wv.z * av.z);
  o[3] = (__bf16)(wv.w * av.w);
  reinterpret_cast<bf16x4*>(wbf)[i] = o;
}

// WT[k][d] = W[d][k]
__global__ __launch_bounds__(256)
void transposeW(const float* __restrict__ W, float* __restrict__ WT){
  __shared__ float tile[32][33];
  const int bx = blockIdx.x, by = blockIdx.y;
  const int tx = threadIdx.x & 31, ty = threadIdx.x >> 5;
  #pragma unroll
  for (int i = 0; i < 4; ++i)
    tile[ty + i*8][tx] = W[(long)(by*32 + ty + i*8) * D1_ + bx*32 + tx];
  __syncthreads();
  #pragma unroll
  for (int i = 0; i < 4; ++i)
    WT[(long)(bx*32 + ty + i*8) * D2_ + by*32 + tx] = tile[tx][ty + i*8];
}

// partial P: part[s][c][k] = sum_{n in slice s, y[n]=c} S[n,k]/(cnt_c+eps)
__global__ __launch_bounds__(256)
void pbuild(const float* __restrict__ S, const int* __restrict__ y,
            const float* __restrict__ cnt, float* __restrict__ part){
  __shared__ float acc[C_ * 256];
  __shared__ float winv[C_];
  const int t = threadIdx.x, kb = blockIdx.x * 256, s = blockIdx.y;
  #pragma unroll
  for (int c = 0; c < C_; ++c) acc[c * 256 + t] = 0.f;
  if (t < C_) winv[t] = 1.f / (cnt[t] + 1e-12f);
  __syncthreads();
  const int n0 = s * 425, n1 = n0 + 425;
  for (int n = n0; n < n1; ++n){
    int c = y[n];
    acc[c * 256 + t] += winv[c] * S[(long)n * D1_ + kb + t];
  }
  #pragma unroll
  for (int c = 0; c < C_; ++c)
    part[((long)s * C_ + c) * D1_ + kb + t] = acc[c * 256 + t];
}

// fused preduce + a2build: A2[ec][k] = (sum_s part[s][c][k]) * alpha[e][k]
__global__ __launch_bounds__(256)
void pa2(const float* __restrict__ part, const float* __restrict__ alpha,
         float* __restrict__ A2){
  int i = blockIdx.x * 256 + threadIdx.x;
  if (i >= EC_ * D1_) return;
  int ec = i >> 11, k = i & (D1_ - 1);
  int e = ec / C_, c = ec - e * C_;
  float s = 0.f;
  #pragma unroll
  for (int kz = 0; kz < 8; ++kz) s += part[((long)kz * C_ + c) * D1_ + k];
  A2[i] = s * alpha[(long)e * D1_ + k];
}

// fused reduceK + centscale: cent[ec][d] = gamma*(sum_kz part2) + bias*s_c
__global__ __launch_bounds__(256)
void redcent(const float* __restrict__ part2, const float* __restrict__ gamma,
             const float* __restrict__ bias, const float* __restrict__ cnt,
             float* __restrict__ cent){
  int i = blockIdx.x * 256 + threadIdx.x;
  if (i >= EC_ * D2_) return;
  int ec = i >> 10, d = i & (D2_ - 1);
  int e = ec / C_, c = ec - e * C_;
  float s = 0.f;
  #pragma unroll
  for (int kz = 0; kz < 8; ++kz) s += part2[(long)kz * EC_ * D2_ + i];
  float sc = cnt[c] / (cnt[c] + 1e-12f);
  cent[i] = gamma[(long)e * D2_ + d] * s + bias[(long)e * D2_ + d] * sc;
}

// fused rownorm_inplace + gcnbuild + bconst_build (one block per ec row)
__global__ __launch_bounds__(256)
void normgcn(float* __restrict__ cent, const float* __restrict__ gamma,
             const float* __restrict__ bias, float* __restrict__ gcn,
             float* __restrict__ bconst){
  const int ec = blockIdx.x, t = threadIdx.x;
  const int e = ec / C_;
  float4* c4 = reinterpret_cast<float4*>(cent + (long)ec * D2_);
  float4 v = c4[t];                       // D2_/4 == 256: one float4 per thread
  float ss = v.x*v.x + v.y*v.y + v.z*v.z + v.w*v.w;
  __shared__ float red[256];
  red[t] = ss; __syncthreads();
  for (int s = 128; s; s >>= 1){ if (t < s) red[t] += red[t + s]; __syncthreads(); }
  float rinv = 1.f / fmaxf(sqrtf(red[0]), 1e-12f);
  v.x *= rinv; v.y *= rinv; v.z *= rinv; v.w *= rinv;
  c4[t] = v;
  float4 g = reinterpret_cast<const float4*>(gamma + (long)e * D2_)[t];
  reinterpret_cast<float4*>(gcn + (long)ec * D2_)[t] =
      make_float4(g.x*v.x, g.y*v.y, g.z*v.z, g.w*v.w);
  float4 bb = reinterpret_cast<const float4*>(bias + (long)e * D2_)[t];
  float bs = bb.x*v.x + bb.y*v.y + bb.z*v.z + bb.w*v.w;
  __syncthreads();
  red[t] = bs; __syncthreads();
  for (int s = 128; s; s >>= 1){ if (t < s) red[t] += red[t + s]; __syncthreads(); }
  if (t == 0) bconst[ec] = red[0];
}

// fused reduceK + gbuild: wbf[NE_+ec][k] = bf16(alpha[e][k] * sum_kz part2)
__global__ __launch_bounds__(256)
void redgb(const float* __restrict__ part2, const float* __restrict__ alpha,
           unsigned short* __restrict__ wbf){
  int i = blockIdx.x * 256 + threadIdx.x;
  if (i >= EC_ * D1_) return;
  int ec = i >> 11, k = i & (D1_ - 1);
  int e = ec / C_;
  float s = 0.f;
  #pragma unroll
  for (int kz = 0; kz < 8; ++kz) s += part2[(long)kz * EC_ * D1_ + i];
  __bf16 b = (__bf16)(alpha[(long)e * D1_ + k] * s);
  wbf[(long)(NE_ + ec) * D1_ + k] = *(unsigned short*)&b;
}

// fp32 vector GEMM, split-K partials
__global__ __launch_bounds__(256)
void gemm64k(const float* __restrict__ A, int lda,
             const float* __restrict__ Bm, int ldb,
             float* __restrict__ part, int M, int N, int KC)
{
  __shared__ float As[16][68];
  __shared__ float Bs[16][68];
  const int kz = blockIdx.z;
  const int m0 = blockIdx.y * 64, n0 = blockIdx.x * 64;
  const int t  = threadIdx.x;
  const int lr = t >> 2;
  const int lk = (t & 3) << 2;
  const int ty4 = (t >> 4) << 2;
  const int tx4 = (t & 15) << 2;
  const bool aok = (m0 + lr) < M;
  const bool bok = (n0 + lr) < N;
  const float* ap = A  + (long)(m0 + lr) * lda + lk;
  const float* bp = Bm + (long)(n0 + lr) * ldb + lk;
  float acc[4][4] = {{0.f}};
  const int k0b = kz * KC, k0e = k0b + KC;
  for (int k0 = k0b; k0 < k0e; k0 += 16){
    float4 av = make_float4(0,0,0,0), bv = make_float4(0,0,0,0);
    if (aok) av = *reinterpret_cast<const float4*>(ap + k0);
    if (bok) bv = *reinterpret_cast<const float4*>(bp + k0);
    As[lk+0][lr] = av.x; As[lk+1][lr] = av.y; As[lk+2][lr] = av.z; As[lk+3][lr] = av.w;
    Bs[lk+0][lr] = bv.x; Bs[lk+1][lr] = bv.y; Bs[lk+2][lr] = bv.z; Bs[lk+3][lr] = bv.w;
    __syncthreads();
    #pragma unroll
    for (int kk = 0; kk < 16; ++kk){
      float4 a = *reinterpret_cast<const float4*>(&As[kk][ty4]);
      float4 b = *reinterpret_cast<const float4*>(&Bs[kk][tx4]);
      float aa[4] = {a.x, a.y, a.z, a.w};
      float bb[4] = {b.x, b.y, b.z, b.w};
      #pragma unroll
      for (int i = 0; i < 4; ++i)
        #pragma unroll
        for (int j = 0; j < 4; ++j)
          acc[i][j] += aa[i] * bb[j];
    }
    __syncthreads();
  }
  float* Out = part + (long)kz * M * N;
  #pragma unroll
  for (int i = 0; i < 4; ++i){
    int m = m0 + ty4 + i;
    if (m >= M) continue;
    #pragma unroll
    for (int j = 0; j < 4; ++j){
      int n = n0 + tx4 + j;
      if (n >= N) continue;
      Out[(long)m * N + n] = acc[i][j];
    }
  }
}

// ======== 8-phase shared core macros (256x256, BK=64, NT=32 K-tiles) ========
#define SA0(buf, kt) { gload_lds16(a0p+(kt)*64, &LA[buf][d00]); gload_lds16(a0p+(kt)*64+32, &LA[buf][d01]); }
#define SA1(buf, kt) { gload_lds16(a1p+(kt)*64, &LA[buf][d10]); gload_lds16(a1p+(kt)*64+32, &LA[buf][d11]); }
#define SB0(buf, kt) { gload_lds16(b0p+(kt)*64, &LB[buf][d00]); gload_lds16(b0p+(kt)*64+32, &LB[buf][d01]); }
#define SB1(buf, kt) { gload_lds16(b1p+(kt)*64, &LB[buf][d10]); gload_lds16(b1p+(kt)*64+32, &LB[buf][d11]); }

#define RD_A03(cb) { _Pragma("unroll") for (int i = 0; i < 4; ++i){ \
    ar[i][0] = *(const bf16x8*)&LA[cb][raB + (unsigned)(i*2  )*512]; \
    ar[i][1] = *(const bf16x8*)&LA[cb][raB + (unsigned)(i*2+1)*512]; } }
#define RD_A47(cb) { _Pragma("unroll") for (int i = 0; i < 4; ++i){ \
    ar[i][0] = *(const bf16x8*)&LA[cb][raB + (unsigned)((4+i)*2  )*512]; \
    ar[i][1] = *(const bf16x8*)&LA[cb][raB + (unsigned)((4+i)*2+1)*512]; } }
#define RD_B01(cb) { _Pragma("unroll") for (int j = 0; j < 2; ++j){ \
    brA[j][0] = *(const bf16x8*)&LB[cb][rbB + (unsigned)(j*2  )*512]; \
    brA[j][1] = *(const bf16x8*)&LB[cb][rbB + (unsigned)(j*2+1)*512]; } }
#define RD_B23(cb) { _Pragma("unroll") for (int j = 0; j < 2; ++j){ \
    brB[j][0] = *(const bf16x8*)&LB[cb][rbB + (unsigned)((2+j)*2  )*512]; \
    brB[j][1] = *(const bf16x8*)&LB[cb][rbB + (unsigned)((2+j)*2+1)*512]; } }

#define MM_Q0 { _Pragma("unroll") for (int ks = 0; ks < 2; ++ks) \
    _Pragma("unroll") for (int i = 0; i < 4; ++i) \
    _Pragma("unroll") for (int j = 0; j < 2; ++j) \
      acc[i][j] = MFMA_(ar[i][ks], brA[j][ks], acc[i][j]); }
#define MM_Q1 { _Pragma("unroll") for (int ks = 0; ks < 2; ++ks) \
    _Pragma("unroll") for (int i = 0; i < 4; ++i) \
    _Pragma("unroll") for (int j = 0; j < 2; ++j) \
      acc[i][2+j] = MFMA_(ar[i][ks], brB[j][ks], acc[i][2+j]); }
#define MM_Q2 { _Pragma("unroll") for (int ks = 0; ks < 2; ++ks) \
    _Pragma("unroll") for (int i = 0; i < 4; ++i) \
    _Pragma("unroll") for (int j = 0; j < 2; ++j) \
      acc[4+i][2+j] = MFMA_(ar[i][ks], brB[j][ks], acc[4+i][2+j]); }
#define MM_Q3 { _Pragma("unroll") for (int ks = 0; ks < 2; ++ks) \
    _Pragma("unroll") for (int i = 0; i < 4; ++i) \
    _Pragma("unroll") for (int j = 0; j < 2; ++j) \
      acc[4+i][j] = MFMA_(ar[i][ks], brA[j][ks], acc[4+i][j]); }

#define PH_TAIL \
  __builtin_amdgcn_s_barrier(); \
  asm volatile("s_waitcnt lgkmcnt(0)" ::: "memory"); \
  __builtin_amdgcn_sched_barrier(0); \
  __builtin_amdgcn_s_setprio(1);
#define PH_END \
  __builtin_amdgcn_s_setprio(0); \
  __builtin_amdgcn_s_barrier();
#define PH_END_W(more) \
  __builtin_amdgcn_s_setprio(0); \
  if (more) asm volatile("s_waitcnt vmcnt(4)" ::: "memory"); \
  else      asm volatile("s_waitcnt vmcnt(0)" ::: "memory"); \
  __builtin_amdgcn_sched_barrier(0); \
  __builtin_amdgcn_s_barrier();

#define K8_LOOP \
  bf16x8 ar[4][2], brA[2][2], brB[2][2]; \
  SA0(0, 0); SA1(0, 0); SB0(0, 0); SB1(0, 0); \
  SB0(1, 1); SB1(1, 1); \
  asm volatile("s_waitcnt vmcnt(4)" ::: "memory"); \
  __builtin_amdgcn_sched_barrier(0); \
  __builtin_amdgcn_s_barrier(); \
  for (int it = 0; it < 16; ++it){ \
    const int kt = it * 2; \
    const bool more = (it < 15); \
    RD_A03(0); RD_B01(0); SA0(1, kt + 1); \
    PH_TAIL; MM_Q0; PH_END; \
    RD_B23(0); SA1(1, kt + 1); \
    PH_TAIL; MM_Q1; PH_END; \
    RD_A47(0); if (more) SB0(0, kt + 2); \
    PH_TAIL; MM_Q2; PH_END; \
    if (more) SB1(0, kt + 2); \
    PH_TAIL; MM_Q3; PH_END_W(more); \
    RD_A03(1); RD_B01(1); if (more) SA0(0, kt + 2); \
    PH_TAIL; MM_Q0; PH_END; \
    RD_B23(1); if (more) SA1(0, kt + 2); \
    PH_TAIL; MM_Q1; PH_END; \
    RD_A47(1); if (more) SB0(1, kt + 3); \
    PH_TAIL; MM_Q2; PH_END; \
    if (more) SB1(1, kt + 3); \
    PH_TAIL; MM_Q3; PH_END_W(more); \
  }

// bijective XCD-chunked remap of the flattened block id (m204)
#define XCD_SWZ(wgid_out) \
  const int gx_ = gridDim.x; \
  const int nwg_ = gx_ * gridDim.y; \
  int bidf_ = blockIdx.y * gx_ + blockIdx.x; \
  const int q_ = nwg_ >> 3, r_ = nwg_ & 7; \
  int xcd_ = bidf_ & 7, pos_ = bidf_ >> 3; \
  int wgid_out = (xcd_ < r_ ? xcd_ * (q_ + 1) : r_ * (q_ + 1) + (xcd_ - r_) * q_) + pos_;

// ==== approx scores GEMM (bf16 single-term), 8-phase 256x256 BK=64 ====
__global__ __launch_bounds__(512)
void sc2(const unsigned short* __restrict__ zh, const unsigned short* __restrict__ sh,
         const float* __restrict__ zinv, const float* __restrict__ sinv,
         float* __restrict__ Out)
{
  __shared__ unsigned short LA[2][16384];
  __shared__ unsigned short LB[2][16384];
  XCD_SWZ(wgid)
  const int n0 = (wgid % gx_) * 256;
  const int m0 = (wgid / gx_) * 256;
  const int t = threadIdx.x, lane = t & 63, w = t >> 6;
  const int wm = w >> 2, wn = w & 3;
  const int r15 = lane & 15, kb = lane >> 4;

  const unsigned short* a0p = zh + (long)(m0 +       w*16 + r15) * D1_ + kb*8;
  const unsigned short* a1p = zh + (long)(m0 + 128 + w*16 + r15) * D1_ + kb*8;
  const unsigned short* b0p = sh + (long)(n0 +       w*16 + r15) * D1_ + kb*8;
  const unsigned short* b1p = sh + (long)(n0 + 128 + w*16 + r15) * D1_ + kb*8;
  const unsigned d00 = (unsigned)(w*2)*512,     d01 = (unsigned)(w*2+1)*512;
  const unsigned d10 = (unsigned)((8+w)*2)*512, d11 = (unsigned)((8+w)*2+1)*512;
  const unsigned raB = (unsigned)wm*8192 + (unsigned)lane*8;
  const unsigned rbB = (unsigned)wn*4096 + (unsigned)lane*8;

  f32x4 acc[8][4];
  #pragma unroll
  for (int i = 0; i < 8; ++i)
    #pragma unroll
    for (int j = 0; j < 4; ++j)
      acc[i][j] = (f32x4){0.f, 0.f, 0.f, 0.f};

  K8_LOOP

  const int mb = m0 + wm * 128 + kb * 4;
  const int nc0 = n0 + wn * 64 + r15;
  #pragma unroll
  for (int j = 0; j < 4; ++j){
    int n = nc0 + j * 16;
    if (n >= N_) continue;
    float si = sinv[n];
    #pragma unroll
    for (int i = 0; i < 8; ++i)
      #pragma unroll
      for (int r = 0; r < 4; ++r){
        int m = mb + i*16 + r;
        Out[(long)m * N_ + n] = acc[i][j][r] * zinv[m] * si;
      }
  }
}

// ==== Fused norm+dot GEMM, 8-phase 256x256 BK=64 ====
__global__ __launch_bounds__(512)
void nd2(const unsigned short* __restrict__ A,
         const unsigned short* __restrict__ Bw,
         const float* __restrict__ gamma,   // [NE_]
         const float* __restrict__ bias,    // [NE_]
         float* __restrict__ norm2,         // [MR_][E_]
         float* __restrict__ dots)          // [MR_][NDOT_]
{
  __shared__ unsigned short LA[2][16384];
  __shared__ unsigned short LB[2][16384];
  XCD_SWZ(wgid)
  const int n0 = (wgid % gx_) * 256;
  const int m0 = (wgid / gx_) * 256;
  const int t = threadIdx.x, lane = t & 63, w = t >> 6;
  const int wm = w >> 2, wn = w & 3;
  const int r15 = lane & 15, kb = lane >> 4;

  const unsigned short* a0p = A  + (long)(m0 +       w*16 + r15) * D1_ + kb*8;
  const unsigned short* a1p = A  + (long)(m0 + 128 + w*16 + r15) * D1_ + kb*8;
  const unsigned short* b0p = Bw + (long)(n0 +       w*16 + r15) * D1_ + kb*8;
  const unsigned short* b1p = Bw + (long)(n0 + 128 + w*16 + r15) * D1_ + kb*8;
  const unsigned d00 = (unsigned)(w*2)*512,     d01 = (unsigned)(w*2+1)*512;
  const unsigned d10 = (unsigned)((8+w)*2)*512, d11 = (unsigned)((8+w)*2+1)*512;
  const unsigned raB = (unsigned)wm*8192 + (unsigned)lane*8;
  const unsigned rbB = (unsigned)wn*4096 + (unsigned)lane*8;

  f32x4 acc[8][4];
  #pragma unroll
  for (int i = 0; i < 8; ++i)
    #pragma unroll
    for (int j = 0; j < 4; ++j)
      acc[i][j] = (f32x4){0.f, 0.f, 0.f, 0.f};

  K8_LOOP

  if (n0 < NE_){
    const int e = n0 >> 10;
    float g4[4], b4[4];
    #pragma unroll
    for (int j = 0; j < 4; ++j){
      int n = n0 + wn * 64 + j * 16 + r15;
      g4[j] = gamma[n]; b4[j] = bias[n];
    }
    float rs[32];
    #pragma unroll
    for (int i = 0; i < 8; ++i)
      #pragma unroll
      for (int r = 0; r < 4; ++r){
        float s = 0.f;
        #pragma unroll
        for (int j = 0; j < 4; ++j){
          float v = acc[i][j][r] * g4[j] + b4[j];
          s += v * v;
        }
        rs[i*4 + r] = s;
      }
    #pragma unroll
    for (int msk = 1; msk < 16; msk <<= 1)
      #pragma unroll
      for (int q = 0; q < 32; ++q) rs[q] += __shfl_xor(rs[q], msk);
    float* red = (float*)&LA[0][0];      // [8][128] floats = 4 KB
    if (r15 == 0){
      #pragma unroll
      for (int i = 0; i < 8; ++i)
        #pragma unroll
        for (int r = 0; r < 4; ++r)
          red[w * 128 + i*16 + kb*4 + r] = rs[i*4 + r];
    }
    __syncthreads();
    if (t < 256){
      int wmg = t >> 7;
      float v = 0.f;
      #pragma unroll
      for (int q = 0; q < 4; ++q)
        v += red[(wmg*4 + q) * 128 + (t & 127)];
      atomicAdd(&norm2[(long)(m0 + t) * E_ + e], v);
    }
  } else {
    const int dc0 = n0 - NE_ + wn * 64 + r15;
    const int mb = m0 + wm * 128 + kb * 4;
    #pragma unroll
    for (int j = 0; j < 4; ++j){
      int dc = dc0 + j * 16;
      #pragma unroll
      for (int i = 0; i < 8; ++i)
        #pragma unroll
        for (int r = 0; r < 4; ++r)
          dots[(long)(mb + i*16 + r) * NDOT_ + dc] = acc[i][j][r];
    }
  }
}

// fused: per-wave top-CAND_ (approx) -> wave-0 merge 96->24 -> exact fp32
// rescore -> top-20 set. Candidate set provably identical to block-wide top-24.
__global__ __launch_bounds__(256)
void topk_rescore(const float* __restrict__ scores, const float* __restrict__ z,
                  const float* __restrict__ S, const float* __restrict__ sinv,
                  int* __restrict__ idx){
  const int b = blockIdx.x, t = threadIdx.x;
  const int l = t & 63, wid = t >> 6;
  const float* row = scores + (long)b * N_;
  float v[14];
  #pragma unroll
  for (int j = 0; j < 14; ++j){
    int i = t + j * 256;
    v[j] = (i < N_) ? row[i] : -3.0e38f;
  }
  __shared__ float wval[4 * CAND_];
  __shared__ int   widx[4 * CAND_];
  __shared__ int   cand[CAND_];
  __shared__ float sval[CAND_];
  // phase 1a: each wave selects top-24 of its register subset (no block sync)
  for (int it = 0; it < CAND_; ++it){
    float bv = -3.0e38f; int bj = 0;
    #pragma unroll
    for (int j = 0; j < 14; ++j)
      if (v[j] > bv){ bv = v[j]; bj = j; }
    int bi = t + bj * 256;
    #pragma unroll
    for (int m = 1; m < 64; m <<= 1){
      float ov = __shfl_xor(bv, m);
      int   oi = __shfl_xor(bi, m);
      if (ov > bv || (ov == bv && oi < bi)){ bv = ov; bi = oi; }
    }
    if (l == 0){ wval[wid * CAND_ + it] = bv; widx[wid * CAND_ + it] = bi; }
    const int ot = bi & 255, oj = bi >> 8;     // owner is in this wave
    #pragma unroll
    for (int j = 0; j < 14; ++j)
      if (t == ot && j == oj) v[j] = -3.0e38f;
  }
  __syncthreads();
  // phase 1b: wave 0 merges 96 -> top-24 (same (value desc, idx asc) order)
  if (wid == 0){
    float m0v = wval[l];
    int   m0i = widx[l];
    float m1v = (l < 32) ? wval[64 + l] : -3.0e38f;
    int   m1i = (l < 32) ? widx[64 + l] : 0x7fffffff;
    for (int it = 0; it < CAND_; ++it){
      float bv = m0v; int bi = m0i; int sel = 0;
      if (m1v > bv || (m1v == bv && m1i < bi)){ bv = m1v; bi = m1i; sel = 1; }
      int bl = l;
      #pragma unroll
      for (int m = 1; m < 64; m <<= 1){
        float ov = __shfl_xor(bv, m);
        int   oi = __shfl_xor(bi, m);
        int   ol = __shfl_xor(bl, m);
        int   os = __shfl_xor(sel, m);
        if (ov > bv || (ov == bv && oi < bi)){ bv = ov; bi = oi; bl = ol; sel = os; }
      }
      if (l == 0) cand[it] = bi;
      if (l == bl){ if (sel) m1v = -3.0e38f; else m0v = -3.0e38f; }
    }
  }
  __syncthreads();
  // phase 2: exact fp32 rescore (4 waves x CAND_/4 candidates)
  const float4* zr = reinterpret_cast<const float4*>(z + (long)b * D1_);
  for (int ci = wid; ci < CAND_; ci += 4){
    int n = cand[ci];
    const float4* sr = reinterpret_cast<const float4*>(S + (long)n * D1_);
    float p = 0.f;
    #pragma unroll
    for (int j = 0; j < 8; ++j){
      float4 a = zr[l + j * 64];
      float4 c = sr[l + j * 64];
      p += a.x*c.x + a.y*c.y + a.z*c.z + a.w*c.w;
    }
    p = wsum64(p);
    if (l == 0) sval[ci] = p * sinv[n];
  }
  __syncthreads();
  // phase 3: exact top-20 of CAND_ (wave 0)
  if (t < 64){
    float vv = (l < CAND_) ? sval[l] : -3.0e38f;
    int   nn = (l < CAND_) ? cand[l] : 0x7fffffff;
    for (int it = 0; it < TOPK_; ++it){
      float bv = vv; int bi = nn, bl = l;
      #pragma unroll
      for (int m = 1; m < 64; m <<= 1){
        float ov = __shfl_xor(bv, m);
        int   oi = __shfl_xor(bi, m);
        int   ol = __shfl_xor(bl, m);
        if (ov > bv || (ov == bv && oi < bi)){ bv = ov; bi = oi; bl = ol; }
      }
      if (l == 0) idx[b * TOPK_ + it] = bi;
      if (l == bl) vv = -3.0e38f;
    }
  }
}

// soft[e][n][c] = softmax_c( TAU*(dots[n][ec]+bconst[ec]) / max(sqrt(norm2[n][e]),eps) )
__global__ __launch_bounds__(256)
void soft_build(const float* __restrict__ dots, const float* __restrict__ norm2,
                const float* __restrict__ bconst, float* __restrict__ soft){
  int id = blockIdx.x * 256 + threadIdx.x;
  if (id >= N_ * E_) return;
  int e = id % E_, n = id / E_;
  float rinv = 1.f / fmaxf(sqrtf(norm2[(long)n * E_ + e]), 1e-12f);
  float tv[C_];
  #pragma unroll
  for (int c = 0; c < C_; ++c)
    tv[c] = TAU_ * (dots[(long)n * NDOT_ + e*C_ + c] + bconst[e*C_ + c]) * rinv;
  float m = tv[0];
  #pragma unroll
  for (int c = 1; c < C_; ++c) m = fmaxf(m, tv[c]);
  float p[C_]; float sum = 0.f;
  #pragma unroll
  for (int c = 0; c < C_; ++c){ p[c] = expf(tv[c] - m); sum += p[c]; }
  float is = 1.f / sum;
  #pragma unroll
  for (int c = 0; c < C_; ++c)
    soft[((long)e * N_ + n) * C_ + c] = p[c] * is;
}

// logits[e][b][c] = TAU*(dots[ZOFF_+b][ec]+bconst[ec]) / max(sqrt(norm2[ZOFF_+b][e]),eps)
__global__ __launch_bounds__(256)
void logits_fin(const float* __restrict__ dots, const float* __restrict__ norm2,
                const float* __restrict__ bconst, float* __restrict__ out){
  int id = blockIdx.x * 256 + threadIdx.x;
  if (id >= B_ * E_) return;
  int e = id % E_, b = id / E_;
  int m = ZOFF_ + b;
  float rinv = 1.f / fmaxf(sqrtf(norm2[(long)m * E_ + e]), 1e-12f);
  float* op = out + (size_t)B_ * C_ + ((long)e * B_ + b) * C_;
  #pragma unroll
  for (int c = 0; c < C_; ++c)
    op[c] = TAU_ * (dots[(long)m * NDOT_ + e*C_ + c] + bconst[e*C_ + c]) * rinv;
}

__global__ __launch_bounds__(256)
void outputs_k(const float* __restrict__ soft, const int* __restrict__ idx, float* __restrict__ out){
  const int lane = threadIdx.x & 63;
  const int b = blockIdx.x * 4 + (threadIdx.x >> 6);
  const int* id = idx + b * TOPK_;
  float o = 0.f;
  for (int e = 0; e < E_; ++e){
    float S = 0.f;
    const float* se = soft + (long)e * N_ * C_;
    #pragma unroll
    for (int k = 0; k < TOPK_; ++k){
      int n = id[k];
      if (lane < C_) S += se[(long)n * C_ + lane];
    }
    float tot = wsum64(S);
    o += S / (tot + 1e-12f);
  }
  if (lane < C_) out[(long)b * C_ + lane] = o * (1.f / E_);
}

extern "C" void kernel_launch(void* const* d_in, const int* in_sizes, int n_in,
                              void* d_out, int out_size, void* d_ws, size_t ws_size,
                              hipStream_t stream){
  const float* z        = (const float*)d_in[0];
  const float* supports = (const float*)d_in[1];
  const float* labels   = (const float*)d_in[2];
  const float* weight   = (const float*)d_in[3];
  const float* alpha    = (const float*)d_in[4];
  const float* gamma    = (const float*)d_in[5];
  const float* bias     = (const float*)d_in[6];
  float* out = (float*)d_out;

  char* w = (char*)d_ws;
  size_t off = 0;
  auto alloc = [&](size_t bytes)->char*{
    char* p = w + off;
    off = (off + bytes + 255) & ~(size_t)255;
    return p;
  };

  // ---- all-permanent layout (~165 MB) ----
  float* zinv = (float*)alloc((size_t)B_ * 4);
  float* sinv = (float*)alloc((size_t)N_ * 4);
  float* cnt  = (float*)alloc((size_t)C_ * 4);
  int*   y    = (int*)  alloc((size_t)N_ * 4);
  int*   idx  = (int*)  alloc((size_t)B_ * TOPK_ * 4);
  unsigned short* SZ  = (unsigned short*)alloc((size_t)MR_ * D1_ * 2);   // sh rows 0..3455, zh rows 3456..7551
  unsigned short* wbf = (unsigned short*)alloc((size_t)NEX_ * D1_ * 2);  // alphaW + G cols
  float* WT     = (float*)alloc((size_t)D1_ * D2_ * 4);
  float* part   = (float*)alloc((size_t)8 * C_ * D1_ * 4);
  float* A2     = (float*)alloc((size_t)EC_ * D1_ * 4);
  float* cent   = (float*)alloc((size_t)EC_ * D2_ * 4);
  float* gcn    = (float*)alloc((size_t)EC_ * D2_ * 4);
  float* bconst = (float*)alloc((size_t)256 * 4);
  float* scores = (float*)alloc((size_t)B_ * N_ * 4);
  float* dots   = (float*)alloc((size_t)MR_ * NDOT_ * 4);
  float* norm2  = (float*)alloc((size_t)MR_ * E_ * 4);
  float* soft   = (float*)alloc((size_t)E_ * N_ * C_ * 4);
  float* part2  = (float*)alloc((size_t)8 * EC_ * D1_ * 4);   // split-K partials (max N=D1_)
  (void)ws_size; (void)in_sizes; (void)n_in; (void)out_size;

  unsigned short* sh = SZ;
  unsigned short* zh = SZ + (size_t)ZOFF_ * D1_;

  // one fused zero pass: sh pad, z pad, G pad cols, norm2, cnt
  {
    long n0 = 14336, n1 = 32768, n2 = 22016, n3 = 19200, n4 = 5;
    long tot = n0 + n1 + n2 + n3 + n4;
    zfill_all<<<(int)((tot + 255) / 256), 256, 0, stream>>>(
        (uint4*)(sh + (size_t)N_ * D1_), n0,
        (uint4*)(SZ + (size_t)(ZOFF_ + B_) * D1_), n1,
        (uint4*)(wbf + (size_t)(NE_ + EC_) * D1_), n2,
        (uint4*)norm2, n3,
        (uint4*)cnt, n4);
  }
  labelprep<<<(N_ + 255) / 256, 256, 0, stream>>>(labels, y, cnt);

  // fused norm + bf16 convert (one pass per input)
  prep_rows<<<B_, 256, 0, stream>>>(z, zh, zinv);
  prep_rows<<<N_, 256, 0, stream>>>(supports, sh, sinv);
  wfold<<<(int)((long)NE_ * D1_ / 4 / 256), 256, 0, stream>>>(weight, alpha, wbf);
  transposeW<<<dim3(D1_ / 32, D2_ / 32), 256, 0, stream>>>(weight, WT);

  // approx scores + fused candidate-select/exact-rescore -> top-20 set
  sc2<<<dim3(NP2_ / 256, B_ / 256, 1), 512, 0, stream>>>(
      zh, sh, zinv, sinv, scores);
  topk_rescore<<<B_, 256, 0, stream>>>(scores, z, supports, sinv, idx);

  // centroid path (fp32, low-rank)
  pbuild<<<dim3(D1_ / 256, 8), 256, 0, stream>>>(supports, y, cnt, part);
  pa2<<<(EC_ * D1_ + 255) / 256, 256, 0, stream>>>(part, alpha, A2);
  gemm64k<<<dim3(D2_ / 64, 3, 8), 256, 0, stream>>>(
      A2, D1_, weight, D1_, part2, EC_, D2_, 256);
  redcent<<<(EC_ * D2_ + 255) / 256, 256, 0, stream>>>(part2, gamma, bias, cnt, cent);
  normgcn<<<EC_, 256, 0, stream>>>(cent, gamma, bias, gcn, bconst);
  gemm64k<<<dim3(D1_ / 64, 3, 8), 256, 0, stream>>>(
      gcn, D2_, WT, D2_, part2, EC_, D1_, 128);
  redgb<<<(EC_ * D1_ + 255) / 256, 256, 0, stream>>>(part2, alpha, wbf);

  // fused norm+dot GEMM over all S and z rows (8-phase, XCD-swizzled)
  nd2<<<dim3(NEX_ / 256, MR_ / 256, 1), 512, 0, stream>>>(
      SZ, wbf, gamma, bias, norm2, dots);

  // finalize
  soft_build<<<(N_ * E_ + 255) / 256, 256, 0, stream>>>(dots, norm2, bconst, soft);
  outputs_k<<<B_ / 4, 256, 0, stream>>>(soft, idx, out);
  logits_fin<<<(B_ * E_ + 255) / 256, 256, 0, stream>>>(dots, norm2, bconst, out);
}

// Round 20
// 897.141 us; speedup vs baseline: 1.0205x; 1.0205x over previous
//
#include <hip/hip_runtime.h>
#include <math.h>

#define B_    4096
#define N_    3400
#define NP2_  3584          // scores N padded to 256 (over-read, cols discarded)
#define D1_   2048
#define D2_   1024
#define E_    10
#define NE_   (E_ * D2_)    // 10240 fused ensemble columns
#define NDOT_ 256           // extra dot columns (170 used)
#define NEX_  (NE_ + NDOT_) // 10496
#define ZOFF_ 3456          // z rows start in SZ
#define MR_   7680          // SZ total rows (3456 S + 4096 z + 128 pad)
#define EC_   170           // E_*C_
#define C_    17
#define TOPK_ 20
#define CAND_ 24            // bf16-score candidates kept for exact rescore
#define TAU_  10.0f

typedef __bf16 bf16x8 __attribute__((ext_vector_type(8)));
typedef __bf16 bf16x4 __attribute__((ext_vector_type(4)));
typedef float  f32x4  __attribute__((ext_vector_type(4)));

#define MFMA_(a,b,c) __builtin_amdgcn_mfma_f32_16x16x32_bf16(a,b,c,0,0,0)

__device__ inline float wsum64(float v){
  #pragma unroll
  for (int m = 1; m < 64; m <<= 1) v += __shfl_xor(v, m);
  return v;
}

__device__ __forceinline__ void gload_lds16(const unsigned short* g, unsigned short* l){
  __builtin_amdgcn_global_load_lds(
      (const __attribute__((address_space(1))) void*)g,
      (__attribute__((address_space(3))) void*)l, 16, 0, 0);
}

// fused: row 1/max(||x||,eps) + fp32 -> hi bf16, one pass
__global__ __launch_bounds__(256)
void prep_rows(const float* __restrict__ X, unsigned short* __restrict__ hi,
               float* __restrict__ rinv){
  const int r = blockIdx.x, t = threadIdx.x;
  const float4* x4 = reinterpret_cast<const float4*>(X + (long)r * D1_);
  bf16x4* h4 = reinterpret_cast<bf16x4*>(hi + (long)r * D1_);
  float ss = 0.f;
  #pragma unroll
  for (int it = 0; it < 2; ++it){
    int i = t + it * 256;
    float4 v = x4[i];
    float f[4] = {v.x, v.y, v.z, v.w};
    bf16x4 h;
    #pragma unroll
    for (int j = 0; j < 4; ++j){
      ss += f[j] * f[j];
      h[j] = (__bf16)f[j];
    }
    h4[i] = h;
  }
  __shared__ float red[256];
  red[t] = ss; __syncthreads();
  for (int s = 128; s; s >>= 1){ if (t < s) red[t] += red[t + s]; __syncthreads(); }
  if (t == 0) rinv[r] = 1.f / fmaxf(sqrtf(red[0]), 1e-12f);
}

// one kernel zeroing all pad/accumulator regions
__global__ __launch_bounds__(256)
void zfill_all(uint4* p0, long n0, uint4* p1, long n1, uint4* p2, long n2,
               uint4* p3, long n3, uint4* p4, long n4){
  long i = (long)blockIdx.x * 256 + threadIdx.x;
  uint4 zz = make_uint4(0,0,0,0);
  if (i < n0){ p0[i] = zz; return; } i -= n0;
  if (i < n1){ p1[i] = zz; return; } i -= n1;
  if (i < n2){ p2[i] = zz; return; } i -= n2;
  if (i < n3){ p3[i] = zz; return; } i -= n3;
  if (i < n4){ p4[i] = zz; }
}

__global__ __launch_bounds__(256)
void labelprep(const float* __restrict__ labels, int* __restrict__ y, float* __restrict__ cnt){
  int n = blockIdx.x * 256 + threadIdx.x;
  if (n >= N_) return;
  int c = 0;
  #pragma unroll
  for (int cc = 0; cc < C_; ++cc) if (labels[n * C_ + cc] > 0.5f) c = cc;
  y[n] = c;
  atomicAdd(&cnt[c], 1.0f);
}

// Wbf[e][n][k] = bf16(alpha[e][k] * W[n][k]),  laid out [NE_][D1_]
__global__ __launch_bounds__(256)
void wfold(const float* __restrict__ W, const float* __restrict__ alpha,
           unsigned short* __restrict__ wbf){
  long i = (long)blockIdx.x * 256 + threadIdx.x;       // float4 units
  const long perE = (long)D2_ * D1_ / 4;
  int e = (int)(i / perE);
  long r = i - (long)e * perE;
  int k4 = (int)(r & (D1_/4 - 1));
  float4 wv = reinterpret_cast<const float4*>(W)[r];
  float4 av = reinterpret_cast<const float4*>(alpha + (long)e * D1_)[k4];
  bf16x4 o;
  o[0] = (__bf16)(wv.x * av.x);
  o[1] = (__bf16)(wv.y * av.y);
  o[2] = (__bf16)(wv.z * av.z);
  o[3] = (__bf16)(wv.w * av.w);
  reinterpret_cast<bf16x4*>(wbf)[i] = o;
}

// WT[k][d] = W[d][k]
__global__ __launch_bounds__(256)
void transposeW(const float* __restrict__ W, float* __restrict__ WT){
  __shared__ float tile[32][33];
  const int bx = blockIdx.x, by = blockIdx.y;
  const int tx = threadIdx.x & 31, ty = threadIdx.x >> 5;
  #pragma unroll
  for (int i = 0; i < 4; ++i)
    tile[ty + i*8][tx] = W[(long)(by*32 + ty + i*8) * D1_ + bx*32 + tx];
  __syncthreads();
  #pragma unroll
  for (int i = 0; i < 4; ++i)
    WT[(long)(bx*32 + ty + i*8) * D2_ + by*32 + tx] = tile[tx][ty + i*8];
}

// partial P: part[s][c][k] = sum_{n in slice s, y[n]=c} S[n,k]/(cnt_c+eps)
__global__ __launch_bounds__(256)
void pbuild(const float* __restrict__ S, const int* __restrict__ y,
            const float* __restrict__ cnt, float* __restrict__ part){
  __shared__ float acc[C_ * 256];
  __shared__ float winv[C_];
  const int t = threadIdx.x, kb = blockIdx.x * 256, s = blockIdx.y;
  #pragma unroll
  for (int c = 0; c < C_; ++c) acc[c * 256 + t] = 0.f;
  if (t < C_) winv[t] = 1.f / (cnt[t] + 1e-12f);
  __syncthreads();
  const int n0 = s * 425, n1 = n0 + 425;
  for (int n = n0; n < n1; ++n){
    int c = y[n];
    acc[c * 256 + t] += winv[c] * S[(long)n * D1_ + kb + t];
  }
  #pragma unroll
  for (int c = 0; c < C_; ++c)
    part[((long)s * C_ + c) * D1_ + kb + t] = acc[c * 256 + t];
}

// fused preduce + a2build: A2[ec][k] = (sum_s part[s][c][k]) * alpha[e][k]
__global__ __launch_bounds__(256)
void pa2(const float* __restrict__ part, const float* __restrict__ alpha,
         float* __restrict__ A2){
  int i = blockIdx.x * 256 + threadIdx.x;
  if (i >= EC_ * D1_) return;
  int ec = i >> 11, k = i & (D1_ - 1);
  int e = ec / C_, c = ec - e * C_;
  float s = 0.f;
  #pragma unroll
  for (int kz = 0; kz < 8; ++kz) s += part[((long)kz * C_ + c) * D1_ + k];
  A2[i] = s * alpha[(long)e * D1_ + k];
}

// fused reduceK + centscale: cent[ec][d] = gamma*(sum_kz part2) + bias*s_c
__global__ __launch_bounds__(256)
void redcent(const float* __restrict__ part2, const float* __restrict__ gamma,
             const float* __restrict__ bias, const float* __restrict__ cnt,
             float* __restrict__ cent){
  int i = blockIdx.x * 256 + threadIdx.x;
  if (i >= EC_ * D2_) return;
  int ec = i >> 10, d = i & (D2_ - 1);
  int e = ec / C_, c = ec - e * C_;
  float s = 0.f;
  #pragma unroll
  for (int kz = 0; kz < 8; ++kz) s += part2[(long)kz * EC_ * D2_ + i];
  float sc = cnt[c] / (cnt[c] + 1e-12f);
  cent[i] = gamma[(long)e * D2_ + d] * s + bias[(long)e * D2_ + d] * sc;
}

// fused rownorm_inplace + gcnbuild + bconst_build (one block per ec row)
__global__ __launch_bounds__(256)
void normgcn(float* __restrict__ cent, const float* __restrict__ gamma,
             const float* __restrict__ bias, float* __restrict__ gcn,
             float* __restrict__ bconst){
  const int ec = blockIdx.x, t = threadIdx.x;
  const int e = ec / C_;
  float4* c4 = reinterpret_cast<float4*>(cent + (long)ec * D2_);
  float4 v = c4[t];                       // D2_/4 == 256: one float4 per thread
  float ss = v.x*v.x + v.y*v.y + v.z*v.z + v.w*v.w;
  __shared__ float red[256];
  red[t] = ss; __syncthreads();
  for (int s = 128; s; s >>= 1){ if (t < s) red[t] += red[t + s]; __syncthreads(); }
  float rinv = 1.f / fmaxf(sqrtf(red[0]), 1e-12f);
  v.x *= rinv; v.y *= rinv; v.z *= rinv; v.w *= rinv;
  c4[t] = v;
  float4 g = reinterpret_cast<const float4*>(gamma + (long)e * D2_)[t];
  reinterpret_cast<float4*>(gcn + (long)ec * D2_)[t] =
      make_float4(g.x*v.x, g.y*v.y, g.z*v.z, g.w*v.w);
  float4 bb = reinterpret_cast<const float4*>(bias + (long)e * D2_)[t];
  float bs = bb.x*v.x + bb.y*v.y + bb.z*v.z + bb.w*v.w;
  __syncthreads();
  red[t] = bs; __syncthreads();
  for (int s = 128; s; s >>= 1){ if (t < s) red[t] += red[t + s]; __syncthreads(); }
  if (t == 0) bconst[ec] = red[0];
}

// fused reduceK + gbuild: wbf[NE_+ec][k] = bf16(alpha[e][k] * sum_kz part2)
__global__ __launch_bounds__(256)
void redgb(const float* __restrict__ part2, const float* __restrict__ alpha,
           unsigned short* __restrict__ wbf){
  int i = blockIdx.x * 256 + threadIdx.x;
  if (i >= EC_ * D1_) return;
  int ec = i >> 11, k = i & (D1_ - 1);
  int e = ec / C_;
  float s = 0.f;
  #pragma unroll
  for (int kz = 0; kz < 8; ++kz) s += part2[(long)kz * EC_ * D1_ + i];
  __bf16 b = (__bf16)(alpha[(long)e * D1_ + k] * s);
  wbf[(long)(NE_ + ec) * D1_ + k] = *(unsigned short*)&b;
}

// fp32 vector GEMM, split-K partials
__global__ __launch_bounds__(256)
void gemm64k(const float* __restrict__ A, int lda,
             const float* __restrict__ Bm, int ldb,
             float* __restrict__ part, int M, int N, int KC)
{
  __shared__ float As[16][68];
  __shared__ float Bs[16][68];
  const int kz = blockIdx.z;
  const int m0 = blockIdx.y * 64, n0 = blockIdx.x * 64;
  const int t  = threadIdx.x;
  const int lr = t >> 2;
  const int lk = (t & 3) << 2;
  const int ty4 = (t >> 4) << 2;
  const int tx4 = (t & 15) << 2;
  const bool aok = (m0 + lr) < M;
  const bool bok = (n0 + lr) < N;
  const float* ap = A  + (long)(m0 + lr) * lda + lk;
  const float* bp = Bm + (long)(n0 + lr) * ldb + lk;
  float acc[4][4] = {{0.f}};
  const int k0b = kz * KC, k0e = k0b + KC;
  for (int k0 = k0b; k0 < k0e; k0 += 16){
    float4 av = make_float4(0,0,0,0), bv = make_float4(0,0,0,0);
    if (aok) av = *reinterpret_cast<const float4*>(ap + k0);
    if (bok) bv = *reinterpret_cast<const float4*>(bp + k0);
    As[lk+0][lr] = av.x; As[lk+1][lr] = av.y; As[lk+2][lr] = av.z; As[lk+3][lr] = av.w;
    Bs[lk+0][lr] = bv.x; Bs[lk+1][lr] = bv.y; Bs[lk+2][lr] = bv.z; Bs[lk+3][lr] = bv.w;
    __syncthreads();
    #pragma unroll
    for (int kk = 0; kk < 16; ++kk){
      float4 a = *reinterpret_cast<const float4*>(&As[kk][ty4]);
      float4 b = *reinterpret_cast<const float4*>(&Bs[kk][tx4]);
      float aa[4] = {a.x, a.y, a.z, a.w};
      float bb[4] = {b.x, b.y, b.z, b.w};
      #pragma unroll
      for (int i = 0; i < 4; ++i)
        #pragma unroll
        for (int j = 0; j < 4; ++j)
          acc[i][j] += aa[i] * bb[j];
    }
    __syncthreads();
  }
  float* Out = part + (long)kz * M * N;
  #pragma unroll
  for (int i = 0; i < 4; ++i){
    int m = m0 + ty4 + i;
    if (m >= M) continue;
    #pragma unroll
    for (int j = 0; j < 4; ++j){
      int n = n0 + tx4 + j;
      if (n >= N) continue;
      Out[(long)m * N + n] = acc[i][j];
    }
  }
}

// ======== 8-phase shared core macros (256x256, BK=64, NT=32 K-tiles) ========
// Stages: one 16KB half-tile per phase; counted vmcnt(4) at phases 4/8.
// ph0/1: (kt+1).A h0/h1 -> buf1 ; ph2/3: (kt+2).B -> buf0 ;
// ph4/5: (kt+2).A -> buf0 ; ph6/7: (kt+3).B -> buf1.  (kt even; buf0=even tiles)
#define SA0(buf, kt) { gload_lds16(a0p+(kt)*64, &LA[buf][d00]); gload_lds16(a0p+(kt)*64+32, &LA[buf][d01]); }
#define SA1(buf, kt) { gload_lds16(a1p+(kt)*64, &LA[buf][d10]); gload_lds16(a1p+(kt)*64+32, &LA[buf][d11]); }
#define SB0(buf, kt) { gload_lds16(b0p+(kt)*64, &LB[buf][d00]); gload_lds16(b0p+(kt)*64+32, &LB[buf][d01]); }
#define SB1(buf, kt) { gload_lds16(b1p+(kt)*64, &LB[buf][d10]); gload_lds16(b1p+(kt)*64+32, &LB[buf][d11]); }

#define RD_A03(cb) { _Pragma("unroll") for (int i = 0; i < 4; ++i){ \
    ar[i][0] = *(const bf16x8*)&LA[cb][raB + (unsigned)(i*2  )*512]; \
    ar[i][1] = *(const bf16x8*)&LA[cb][raB + (unsigned)(i*2+1)*512]; } }
#define RD_A47(cb) { _Pragma("unroll") for (int i = 0; i < 4; ++i){ \
    ar[i][0] = *(const bf16x8*)&LA[cb][raB + (unsigned)((4+i)*2  )*512]; \
    ar[i][1] = *(const bf16x8*)&LA[cb][raB + (unsigned)((4+i)*2+1)*512]; } }
#define RD_B01(cb) { _Pragma("unroll") for (int j = 0; j < 2; ++j){ \
    brA[j][0] = *(const bf16x8*)&LB[cb][rbB + (unsigned)(j*2  )*512]; \
    brA[j][1] = *(const bf16x8*)&LB[cb][rbB + (unsigned)(j*2+1)*512]; } }
#define RD_B23(cb) { _Pragma("unroll") for (int j = 0; j < 2; ++j){ \
    brB[j][0] = *(const bf16x8*)&LB[cb][rbB + (unsigned)((2+j)*2  )*512]; \
    brB[j][1] = *(const bf16x8*)&LB[cb][rbB + (unsigned)((2+j)*2+1)*512]; } }

#define MM_Q0 { _Pragma("unroll") for (int ks = 0; ks < 2; ++ks) \
    _Pragma("unroll") for (int i = 0; i < 4; ++i) \
    _Pragma("unroll") for (int j = 0; j < 2; ++j) \
      acc[i][j] = MFMA_(ar[i][ks], brA[j][ks], acc[i][j]); }
#define MM_Q1 { _Pragma("unroll") for (int ks = 0; ks < 2; ++ks) \
    _Pragma("unroll") for (int i = 0; i < 4; ++i) \
    _Pragma("unroll") for (int j = 0; j < 2; ++j) \
      acc[i][2+j] = MFMA_(ar[i][ks], brB[j][ks], acc[i][2+j]); }
#define MM_Q2 { _Pragma("unroll") for (int ks = 0; ks < 2; ++ks) \
    _Pragma("unroll") for (int i = 0; i < 4; ++i) \
    _Pragma("unroll") for (int j = 0; j < 2; ++j) \
      acc[4+i][2+j] = MFMA_(ar[i][ks], brB[j][ks], acc[4+i][2+j]); }
#define MM_Q3 { _Pragma("unroll") for (int ks = 0; ks < 2; ++ks) \
    _Pragma("unroll") for (int i = 0; i < 4; ++i) \
    _Pragma("unroll") for (int j = 0; j < 2; ++j) \
      acc[4+i][j] = MFMA_(ar[i][ks], brA[j][ks], acc[4+i][j]); }

#define PH_TAIL \
  __builtin_amdgcn_s_barrier(); \
  asm volatile("s_waitcnt lgkmcnt(0)" ::: "memory"); \
  __builtin_amdgcn_sched_barrier(0); \
  __builtin_amdgcn_s_setprio(1);
#define PH_END \
  __builtin_amdgcn_s_setprio(0); \
  __builtin_amdgcn_s_barrier();
#define PH_END_W(more) \
  __builtin_amdgcn_s_setprio(0); \
  if (more) asm volatile("s_waitcnt vmcnt(4)" ::: "memory"); \
  else      asm volatile("s_waitcnt vmcnt(0)" ::: "memory"); \
  __builtin_amdgcn_sched_barrier(0); \
  __builtin_amdgcn_s_barrier();

#define K8_LOOP \
  bf16x8 ar[4][2], brA[2][2], brB[2][2]; \
  /* prologue: kt0 all 4 halves + kt1 B halves; retire kt0 (vmcnt(4)) */ \
  SA0(0, 0); SA1(0, 0); SB0(0, 0); SB1(0, 0); \
  SB0(1, 1); SB1(1, 1); \
  asm volatile("s_waitcnt vmcnt(4)" ::: "memory"); \
  __builtin_amdgcn_sched_barrier(0); \
  __builtin_amdgcn_s_barrier(); \
  for (int it = 0; it < 16; ++it){ \
    const int kt = it * 2; \
    const bool more = (it < 15); \
    /* ph0: tile kt q0 */ \
    RD_A03(0); RD_B01(0); SA0(1, kt + 1); \
    PH_TAIL; MM_Q0; PH_END; \
    /* ph1: q1 */ \
    RD_B23(0); SA1(1, kt + 1); \
    PH_TAIL; MM_Q1; PH_END; \
    /* ph2: q2 */ \
    RD_A47(0); if (more) SB0(0, kt + 2); \
    PH_TAIL; MM_Q2; PH_END; \
    /* ph3: q3 + W1 */ \
    if (more) SB1(0, kt + 2); \
    PH_TAIL; MM_Q3; PH_END_W(more); \
    /* ph4: tile kt+1 q0 */ \
    RD_A03(1); RD_B01(1); if (more) SA0(0, kt + 2); \
    PH_TAIL; MM_Q0; PH_END; \
    /* ph5: q1 */ \
    RD_B23(1); if (more) SA1(0, kt + 2); \
    PH_TAIL; MM_Q1; PH_END; \
    /* ph6: q2 */ \
    RD_A47(1); if (more) SB0(1, kt + 3); \
    PH_TAIL; MM_Q2; PH_END; \
    /* ph7: q3 + W2 */ \
    if (more) SB1(1, kt + 3); \
    PH_TAIL; MM_Q3; PH_END_W(more); \
  }

// ==== approx scores GEMM (bf16 single-term), 8-phase 256x256 BK=64 ====
__global__ __launch_bounds__(512)
void sc2(const unsigned short* __restrict__ zh, const unsigned short* __restrict__ sh,
         const float* __restrict__ zinv, const float* __restrict__ sinv,
         float* __restrict__ Out)
{
  __shared__ unsigned short LA[2][16384];
  __shared__ unsigned short LB[2][16384];
  const int n0 = blockIdx.x * 256;
  const int m0 = blockIdx.y * 256;
  const int t = threadIdx.x, lane = t & 63, w = t >> 6;
  const int wm = w >> 2, wn = w & 3;
  const int r15 = lane & 15, kb = lane >> 4;

  const unsigned short* a0p = zh + (long)(m0 +       w*16 + r15) * D1_ + kb*8;
  const unsigned short* a1p = zh + (long)(m0 + 128 + w*16 + r15) * D1_ + kb*8;
  const unsigned short* b0p = sh + (long)(n0 +       w*16 + r15) * D1_ + kb*8;
  const unsigned short* b1p = sh + (long)(n0 + 128 + w*16 + r15) * D1_ + kb*8;
  const unsigned d00 = (unsigned)(w*2)*512,     d01 = (unsigned)(w*2+1)*512;
  const unsigned d10 = (unsigned)((8+w)*2)*512, d11 = (unsigned)((8+w)*2+1)*512;
  const unsigned raB = (unsigned)wm*8192 + (unsigned)lane*8;
  const unsigned rbB = (unsigned)wn*4096 + (unsigned)lane*8;

  f32x4 acc[8][4];
  #pragma unroll
  for (int i = 0; i < 8; ++i)
    #pragma unroll
    for (int j = 0; j < 4; ++j)
      acc[i][j] = (f32x4){0.f, 0.f, 0.f, 0.f};

  K8_LOOP

  const int mb = m0 + wm * 128 + kb * 4;
  const int nc0 = n0 + wn * 64 + r15;
  #pragma unroll
  for (int j = 0; j < 4; ++j){
    int n = nc0 + j * 16;
    if (n >= N_) continue;
    float si = sinv[n];
    #pragma unroll
    for (int i = 0; i < 8; ++i)
      #pragma unroll
      for (int r = 0; r < 4; ++r){
        int m = mb + i*16 + r;
        Out[(long)m * N_ + n] = acc[i][j][r] * zinv[m] * si;
      }
  }
}

// ==== Fused norm+dot GEMM, 8-phase 256x256 BK=64 ====
__global__ __launch_bounds__(512)
void nd2(const unsigned short* __restrict__ A,
         const unsigned short* __restrict__ Bw,
         const float* __restrict__ gamma,   // [NE_]
         const float* __restrict__ bias,    // [NE_]
         float* __restrict__ norm2,         // [MR_][E_]
         float* __restrict__ dots)          // [MR_][NDOT_]
{
  __shared__ unsigned short LA[2][16384];
  __shared__ unsigned short LB[2][16384];
  const int n0 = blockIdx.x * 256;
  const int m0 = blockIdx.y * 256;
  const int t = threadIdx.x, lane = t & 63, w = t >> 6;
  const int wm = w >> 2, wn = w & 3;
  const int r15 = lane & 15, kb = lane >> 4;

  const unsigned short* a0p = A  + (long)(m0 +       w*16 + r15) * D1_ + kb*8;
  const unsigned short* a1p = A  + (long)(m0 + 128 + w*16 + r15) * D1_ + kb*8;
  const unsigned short* b0p = Bw + (long)(n0 +       w*16 + r15) * D1_ + kb*8;
  const unsigned short* b1p = Bw + (long)(n0 + 128 + w*16 + r15) * D1_ + kb*8;
  const unsigned d00 = (unsigned)(w*2)*512,     d01 = (unsigned)(w*2+1)*512;
  const unsigned d10 = (unsigned)((8+w)*2)*512, d11 = (unsigned)((8+w)*2+1)*512;
  const unsigned raB = (unsigned)wm*8192 + (unsigned)lane*8;
  const unsigned rbB = (unsigned)wn*4096 + (unsigned)lane*8;

  f32x4 acc[8][4];
  #pragma unroll
  for (int i = 0; i < 8; ++i)
    #pragma unroll
    for (int j = 0; j < 4; ++j)
      acc[i][j] = (f32x4){0.f, 0.f, 0.f, 0.f};

  K8_LOOP

  if (n0 < NE_){
    const int e = n0 >> 10;
    float g4[4], b4[4];
    #pragma unroll
    for (int j = 0; j < 4; ++j){
      int n = n0 + wn * 64 + j * 16 + r15;
      g4[j] = gamma[n]; b4[j] = bias[n];
    }
    float rs[32];
    #pragma unroll
    for (int i = 0; i < 8; ++i)
      #pragma unroll
      for (int r = 0; r < 4; ++r){
        float s = 0.f;
        #pragma unroll
        for (int j = 0; j < 4; ++j){
          float v = acc[i][j][r] * g4[j] + b4[j];
          s += v * v;
        }
        rs[i*4 + r] = s;
      }
    #pragma unroll
    for (int msk = 1; msk < 16; msk <<= 1)
      #pragma unroll
      for (int q = 0; q < 32; ++q) rs[q] += __shfl_xor(rs[q], msk);
    float* red = (float*)&LA[0][0];      // [8][128] floats = 4 KB
    if (r15 == 0){
      #pragma unroll
      for (int i = 0; i < 8; ++i)
        #pragma unroll
        for (int r = 0; r < 4; ++r)
          red[w * 128 + i*16 + kb*4 + r] = rs[i*4 + r];
    }
    __syncthreads();
    if (t < 256){
      int wmg = t >> 7;
      float v = 0.f;
      #pragma unroll
      for (int q = 0; q < 4; ++q)
        v += red[(wmg*4 + q) * 128 + (t & 127)];
      atomicAdd(&norm2[(long)(m0 + t) * E_ + e], v);
    }
  } else {
    const int dc0 = n0 - NE_ + wn * 64 + r15;
    const int mb = m0 + wm * 128 + kb * 4;
    #pragma unroll
    for (int j = 0; j < 4; ++j){
      int dc = dc0 + j * 16;
      #pragma unroll
      for (int i = 0; i < 8; ++i)
        #pragma unroll
        for (int r = 0; r < 4; ++r)
          dots[(long)(mb + i*16 + r) * NDOT_ + dc] = acc[i][j][r];
    }
  }
}

// fused: register top-CAND_ on approx scores -> exact fp32 rescore -> top-20 set
__global__ __launch_bounds__(256)
void topk_rescore(const float* __restrict__ scores, const float* __restrict__ z,
                  const float* __restrict__ S, const float* __restrict__ sinv,
                  int* __restrict__ idx){
  const int b = blockIdx.x, t = threadIdx.x;
  const int l = t & 63, wid = t >> 6;
  const float* row = scores + (long)b * N_;
  float v[14];
  #pragma unroll
  for (int j = 0; j < 14; ++j){
    int i = t + j * 256;
    v[j] = (i < N_) ? row[i] : -3.0e38f;
  }
  __shared__ float wv4[4];
  __shared__ int   wi4[4];
  __shared__ int   cand[CAND_];
  __shared__ float sval[CAND_];
  for (int it = 0; it < CAND_; ++it){
    float bv = -3.0e38f; int bj = 0;
    #pragma unroll
    for (int j = 0; j < 14; ++j)
      if (v[j] > bv){ bv = v[j]; bj = j; }
    int bi = t + bj * 256;
    #pragma unroll
    for (int m = 1; m < 64; m <<= 1){
      float ov = __shfl_xor(bv, m);
      int   oi = __shfl_xor(bi, m);
      if (ov > bv || (ov == bv && oi < bi)){ bv = ov; bi = oi; }
    }
    if (l == 0){ wv4[wid] = bv; wi4[wid] = bi; }
    __syncthreads();
    float gv = wv4[0]; int gi = wi4[0];
    #pragma unroll
    for (int k = 1; k < 4; ++k){
      float ov = wv4[k]; int oi = wi4[k];
      if (ov > gv || (ov == gv && oi < gi)){ gv = ov; gi = oi; }
    }
    if (t == 0) cand[it] = gi;
    const int ot = gi & 255, oj = gi >> 8;
    #pragma unroll
    for (int j = 0; j < 14; ++j)
      if (t == ot && j == oj) v[j] = -3.0e38f;
    __syncthreads();
  }
  const float4* zr = reinterpret_cast<const float4*>(z + (long)b * D1_);
  for (int ci = wid; ci < CAND_; ci += 4){
    int n = cand[ci];
    const float4* sr = reinterpret_cast<const float4*>(S + (long)n * D1_);
    float p = 0.f;
    #pragma unroll
    for (int j = 0; j < 8; ++j){
      float4 a = zr[l + j * 64];
      float4 c = sr[l + j * 64];
      p += a.x*c.x + a.y*c.y + a.z*c.z + a.w*c.w;
    }
    p = wsum64(p);
    if (l == 0) sval[ci] = p * sinv[n];
  }
  __syncthreads();
  if (t < 64){
    float vv = (l < CAND_) ? sval[l] : -3.0e38f;
    int   nn = (l < CAND_) ? cand[l] : 0x7fffffff;
    for (int it = 0; it < TOPK_; ++it){
      float bv = vv; int bi = nn, bl = l;
      #pragma unroll
      for (int m = 1; m < 64; m <<= 1){
        float ov = __shfl_xor(bv, m);
        int   oi = __shfl_xor(bi, m);
        int   ol = __shfl_xor(bl, m);
        if (ov > bv || (ov == bv && oi < bi)){ bv = ov; bi = oi; bl = ol; }
      }
      if (l == 0) idx[b * TOPK_ + it] = bi;
      if (l == bl) vv = -3.0e38f;
    }
  }
}

// soft[e][n][c] = softmax_c( TAU*(dots[n][ec]+bconst[ec]) / max(sqrt(norm2[n][e]),eps) )
__global__ __launch_bounds__(256)
void soft_build(const float* __restrict__ dots, const float* __restrict__ norm2,
                const float* __restrict__ bconst, float* __restrict__ soft){
  int id = blockIdx.x * 256 + threadIdx.x;
  if (id >= N_ * E_) return;
  int e = id % E_, n = id / E_;
  float rinv = 1.f / fmaxf(sqrtf(norm2[(long)n * E_ + e]), 1e-12f);
  float tv[C_];
  #pragma unroll
  for (int c = 0; c < C_; ++c)
    tv[c] = TAU_ * (dots[(long)n * NDOT_ + e*C_ + c] + bconst[e*C_ + c]) * rinv;
  float m = tv[0];
  #pragma unroll
  for (int c = 1; c < C_; ++c) m = fmaxf(m, tv[c]);
  float p[C_]; float sum = 0.f;
  #pragma unroll
  for (int c = 0; c < C_; ++c){ p[c] = expf(tv[c] - m); sum += p[c]; }
  float is = 1.f / sum;
  #pragma unroll
  for (int c = 0; c < C_; ++c)
    soft[((long)e * N_ + n) * C_ + c] = p[c] * is;
}

// logits[e][b][c] = TAU*(dots[ZOFF_+b][ec]+bconst[ec]) / max(sqrt(norm2[ZOFF_+b][e]),eps)
__global__ __launch_bounds__(256)
void logits_fin(const float* __restrict__ dots, const float* __restrict__ norm2,
                const float* __restrict__ bconst, float* __restrict__ out){
  int id = blockIdx.x * 256 + threadIdx.x;
  if (id >= B_ * E_) return;
  int e = id % E_, b = id / E_;
  int m = ZOFF_ + b;
  float rinv = 1.f / fmaxf(sqrtf(norm2[(long)m * E_ + e]), 1e-12f);
  float* op = out + (size_t)B_ * C_ + ((long)e * B_ + b) * C_;
  #pragma unroll
  for (int c = 0; c < C_; ++c)
    op[c] = TAU_ * (dots[(long)m * NDOT_ + e*C_ + c] + bconst[e*C_ + c]) * rinv;
}

__global__ __launch_bounds__(256)
void outputs_k(const float* __restrict__ soft, const int* __restrict__ idx, float* __restrict__ out){
  const int lane = threadIdx.x & 63;
  const int b = blockIdx.x * 4 + (threadIdx.x >> 6);
  const int* id = idx + b * TOPK_;
  float o = 0.f;
  for (int e = 0; e < E_; ++e){
    float S = 0.f;
    const float* se = soft + (long)e * N_ * C_;
    #pragma unroll
    for (int k = 0; k < TOPK_; ++k){
      int n = id[k];
      if (lane < C_) S += se[(long)n * C_ + lane];
    }
    float tot = wsum64(S);
    o += S / (tot + 1e-12f);
  }
  if (lane < C_) out[(long)b * C_ + lane] = o * (1.f / E_);
}

extern "C" void kernel_launch(void* const* d_in, const int* in_sizes, int n_in,
                              void* d_out, int out_size, void* d_ws, size_t ws_size,
                              hipStream_t stream){
  const float* z        = (const float*)d_in[0];
  const float* supports = (const float*)d_in[1];
  const float* labels   = (const float*)d_in[2];
  const float* weight   = (const float*)d_in[3];
  const float* alpha    = (const float*)d_in[4];
  const float* gamma    = (const float*)d_in[5];
  const float* bias     = (const float*)d_in[6];
  float* out = (float*)d_out;

  char* w = (char*)d_ws;
  size_t off = 0;
  auto alloc = [&](size_t bytes)->char*{
    char* p = w + off;
    off = (off + bytes + 255) & ~(size_t)255;
    return p;
  };

  // ---- all-permanent layout (~165 MB) ----
  float* zinv = (float*)alloc((size_t)B_ * 4);
  float* sinv = (float*)alloc((size_t)N_ * 4);
  float* cnt  = (float*)alloc((size_t)C_ * 4);
  int*   y    = (int*)  alloc((size_t)N_ * 4);
  int*   idx  = (int*)  alloc((size_t)B_ * TOPK_ * 4);
  unsigned short* SZ  = (unsigned short*)alloc((size_t)MR_ * D1_ * 2);   // sh rows 0..3455, zh rows 3456..7551
  unsigned short* wbf = (unsigned short*)alloc((size_t)NEX_ * D1_ * 2);  // alphaW + G cols
  float* WT     = (float*)alloc((size_t)D1_ * D2_ * 4);
  float* part   = (float*)alloc((size_t)8 * C_ * D1_ * 4);
  float* A2     = (float*)alloc((size_t)EC_ * D1_ * 4);
  float* cent   = (float*)alloc((size_t)EC_ * D2_ * 4);
  float* gcn    = (float*)alloc((size_t)EC_ * D2_ * 4);
  float* bconst = (float*)alloc((size_t)256 * 4);
  float* scores = (float*)alloc((size_t)B_ * N_ * 4);
  float* dots   = (float*)alloc((size_t)MR_ * NDOT_ * 4);
  float* norm2  = (float*)alloc((size_t)MR_ * E_ * 4);
  float* soft   = (float*)alloc((size_t)E_ * N_ * C_ * 4);
  float* part2  = (float*)alloc((size_t)8 * EC_ * D1_ * 4);   // split-K partials (max N=D1_)
  (void)ws_size; (void)in_sizes; (void)n_in; (void)out_size;

  unsigned short* sh = SZ;
  unsigned short* zh = SZ + (size_t)ZOFF_ * D1_;

  // one fused zero pass: sh pad, z pad, G pad cols, norm2, cnt
  {
    long n0 = 14336, n1 = 32768, n2 = 22016, n3 = 19200, n4 = 5;
    long tot = n0 + n1 + n2 + n3 + n4;
    zfill_all<<<(int)((tot + 255) / 256), 256, 0, stream>>>(
        (uint4*)(sh + (size_t)N_ * D1_), n0,
        (uint4*)(SZ + (size_t)(ZOFF_ + B_) * D1_), n1,
        (uint4*)(wbf + (size_t)(NE_ + EC_) * D1_), n2,
        (uint4*)norm2, n3,
        (uint4*)cnt, n4);
  }
  labelprep<<<(N_ + 255) / 256, 256, 0, stream>>>(labels, y, cnt);

  // fused norm + bf16 convert (one pass per input)
  prep_rows<<<B_, 256, 0, stream>>>(z, zh, zinv);
  prep_rows<<<N_, 256, 0, stream>>>(supports, sh, sinv);
  wfold<<<(int)((long)NE_ * D1_ / 4 / 256), 256, 0, stream>>>(weight, alpha, wbf);
  transposeW<<<dim3(D1_ / 32, D2_ / 32), 256, 0, stream>>>(weight, WT);

  // approx scores + fused candidate-select/exact-rescore -> top-20 set
  sc2<<<dim3(NP2_ / 256, B_ / 256, 1), 512, 0, stream>>>(
      zh, sh, zinv, sinv, scores);
  topk_rescore<<<B_, 256, 0, stream>>>(scores, z, supports, sinv, idx);

  // centroid path (fp32, low-rank)
  pbuild<<<dim3(D1_ / 256, 8), 256, 0, stream>>>(supports, y, cnt, part);
  pa2<<<(EC_ * D1_ + 255) / 256, 256, 0, stream>>>(part, alpha, A2);
  gemm64k<<<dim3(D2_ / 64, 3, 8), 256, 0, stream>>>(
      A2, D1_, weight, D1_, part2, EC_, D2_, 256);
  redcent<<<(EC_ * D2_ + 255) / 256, 256, 0, stream>>>(part2, gamma, bias, cnt, cent);
  normgcn<<<EC_, 256, 0, stream>>>(cent, gamma, bias, gcn, bconst);
  gemm64k<<<dim3(D1_ / 64, 3, 8), 256, 0, stream>>>(
      gcn, D2_, WT, D2_, part2, EC_, D1_, 128);
  redgb<<<(EC_ * D1_ + 255) / 256, 256, 0, stream>>>(part2, alpha, wbf);

  // fused norm+dot GEMM over all S and z rows (8-phase)
  nd2<<<dim3(NEX_ / 256, MR_ / 256, 1), 512, 0, stream>>>(
      SZ, wbf, gamma, bias, norm2, dots);

  // finalize
  soft_build<<<(N_ * E_ + 255) / 256, 256, 0, stream>>>(dots, norm2, bconst, soft);
  outputs_k<<<B_ / 4, 256, 0, stream>>>(soft, idx, out);
  logits_fin<<<(B_ * E_ + 255) / 256, 256, 0, stream>>>(dots, norm2, bconst, out);
}